// Round 2
// baseline (400.893 us; speedup 1.0000x reference)
//
#include <hip/hip_runtime.h>
#include <hip/hip_bf16.h>

#define BATCH 8
#define NDIM  2048
#define MDIM  2048
#define CDIM  128

typedef __attribute__((ext_vector_type(8))) short bf16x8;
typedef __attribute__((ext_vector_type(4))) float f32x4;
// 4B-aligned float4 for the (out+1)-offset misaligned global stores
typedef __attribute__((ext_vector_type(4), aligned(4))) float f32x4u;

__device__ __forceinline__ float bf2f(unsigned int u16){
    union { unsigned int u; float f; } v; v.u = u16 << 16; return v.f;
}
__device__ __forceinline__ unsigned int f2bf(float f){
    union { float f; unsigned int u; } v; v.f = f;
    unsigned int u = v.u;
    u += 0x7FFFu + ((u >> 16) & 1u);   // round-to-nearest-even
    return u >> 16;
}

__global__ void ws_init_kernel(float* wsf){
    wsf[0] = 0.0f;          // loss numerator
    ((int*)wsf)[1] = 0;     // mask count
}

__global__ void finalize_kernel(const float* wsf, float* out){
    out[0] = wsf[0] / (float)(((const int*)wsf)[1]);
}

__global__ __launch_bounds__(256, 5) void cossim_bce_main(
    const int*  __restrict__ zp,
    const float* __restrict__ x1,
    const float* __restrict__ x2,
    const float* __restrict__ tparm,
    const float* __restrict__ bparm,
    float* __restrict__ out,
    float* __restrict__ wsf)
{
    // 32 KB LDS total -> 5 blocks/CU.
    // lA/lB: 128x64 bf16 K-phase tiles (16 KB each), XOR-swizzled.
    // After GEMM: lA reused for norms (1 KB), lB reused for 32x128 f32 cos strip (16 KB).
    __shared__ __align__(16) unsigned short lA[128*64];
    __shared__ __align__(16) unsigned short lB[128*64];

    const int t  = threadIdx.x;
    const int bx = blockIdx.x;   // M tile
    const int by = blockIdx.y;   // N tile
    const int bz = blockIdx.z;   // batch

    const float tv = *tparm;
    const float bv = *bparm;

    const float* x1base = x1 + ((size_t)(bz*NDIM) + by*128) * CDIM;
    const float* x2base = x2 + ((size_t)(bz*MDIM) + bx*128) * CDIM;

    const int lane = t & 63;
    const int w    = t >> 6;
    const int wrow = (w >> 1) * 64;  // wave output row offset
    const int wcol = (w & 1) * 64;   // wave output col offset
    const int quad = lane >> 4;      // 0..3
    const int l16  = lane & 15;

    f32x4 acc[4][4];
    #pragma unroll
    for (int m = 0; m < 4; ++m)
        #pragma unroll
        for (int n = 0; n < 4; ++n)
            acc[m][n] = (f32x4){0.f, 0.f, 0.f, 0.f};

    float nsum = 0.f;                // per-thread norm partial (row t&127 of A or B)
    const int nrow = t & 127;

    // ---- two K-phases of 64 ----
    #pragma unroll
    for (int ph = 0; ph < 2; ++ph){
        // stage: f32 -> bf16, swizzled LDS writes (chunk ^ row&7)
        #pragma unroll
        for (int i = 0; i < 4; ++i){
            int chunk = i*256 + t;       // 1024 16B-chunks per tile
            int row = chunk >> 3;        // 0..127
            int pos = chunk & 7;         // 16B chunk within 64-col row
            int sw  = pos ^ (row & 7);
            {
                const float* p = x1base + row*CDIM + ph*64 + pos*8;
                float4 a = *(const float4*)p;
                float4 b = *(const float4*)(p + 4);
                uint4 pk;
                pk.x = f2bf(a.x) | (f2bf(a.y) << 16);
                pk.y = f2bf(a.z) | (f2bf(a.w) << 16);
                pk.z = f2bf(b.x) | (f2bf(b.y) << 16);
                pk.w = f2bf(b.z) | (f2bf(b.w) << 16);
                ((uint4*)lA)[row*8 + sw] = pk;
            }
            {
                const float* p = x2base + row*CDIM + ph*64 + pos*8;
                float4 a = *(const float4*)p;
                float4 b = *(const float4*)(p + 4);
                uint4 pk;
                pk.x = f2bf(a.x) | (f2bf(a.y) << 16);
                pk.y = f2bf(a.z) | (f2bf(a.w) << 16);
                pk.z = f2bf(b.x) | (f2bf(b.y) << 16);
                pk.w = f2bf(b.z) | (f2bf(b.w) << 16);
                ((uint4*)lB)[row*8 + sw] = pk;
            }
        }
        __syncthreads();

        // MFMA: 2 k-steps of 32 per phase
        #pragma unroll
        for (int kk = 0; kk < 2; ++kk){
            const int kc = kk*4 + quad;          // 16B k-chunk 0..7
            bf16x8 afr[4], bfr[4];
            #pragma unroll
            for (int m = 0; m < 4; ++m){
                int row = wrow + m*16 + l16;
                afr[m] = ((const bf16x8*)lA)[row*8 + (kc ^ (row & 7))];
            }
            #pragma unroll
            for (int n = 0; n < 4; ++n){
                int row = wcol + n*16 + l16;
                bfr[n] = ((const bf16x8*)lB)[row*8 + (kc ^ (row & 7))];
            }
            #pragma unroll
            for (int m = 0; m < 4; ++m)
                #pragma unroll
                for (int n = 0; n < 4; ++n)
                    acc[m][n] = __builtin_amdgcn_mfma_f32_16x16x32_bf16(
                                    afr[m], bfr[n], acc[m][n], 0, 0, 0);
        }

        // norm partials from the bf16 tiles (one row per thread)
        {
            const unsigned short* src = (t < 128) ? lA : lB;
            #pragma unroll
            for (int c = 0; c < 8; ++c){
                uint4 v = ((const uint4*)src)[nrow*8 + (c ^ (nrow & 7))];
                float f0 = bf2f(v.x & 0xffffu), f1 = bf2f(v.x >> 16);
                float f2 = bf2f(v.y & 0xffffu), f3 = bf2f(v.y >> 16);
                float f4 = bf2f(v.z & 0xffffu), f5 = bf2f(v.z >> 16);
                float f6 = bf2f(v.w & 0xffffu), f7 = bf2f(v.w >> 16);
                nsum += f0*f0 + f1*f1 + f2*f2 + f3*f3 + f4*f4 + f5*f5 + f6*f6 + f7*f7;
            }
        }
        __syncthreads();   // tile reads done before restage / nsh reuse
    }

    // ---- norms into LDS (reuse lA) ----
    float* nsh = (float*)lA;         // [0..127]=1/||x1 row||, [128..255]=1/||x2 row||
    nsh[t] = 1.0f / sqrtf(fmaxf(nsum, 1e-16f));
    __syncthreads();

    // ---- epilogue: 4 strips of 32 rows via LDS transpose (reuse lB) ----
    float* cosT = (float*)lB;        // [32][128] f32
    float* cosOut  = out + 1;
    float* maskOut = out + 1 + (size_t)BATCH*NDIM*MDIM;
    const size_t strideBase = (size_t)bz*NDIM*MDIM + (size_t)(by*128)*MDIM + (size_t)(bx*128);

    float lnum = 0.f;
    int   lcnt = 0;

    #pragma unroll
    for (int q = 0; q < 4; ++q){
        // producers: waves owning rows q*32 .. q*32+31
        if ((w >> 1) == (q >> 1)){
            #pragma unroll
            for (int mi = 0; mi < 2; ++mi){
                int m = (q & 1)*2 + mi;
                #pragma unroll
                for (int n = 0; n < 4; ++n){
                    int colL = wcol + n*16 + l16;
                    float in2 = nsh[128 + colL];
                    #pragma unroll
                    for (int r = 0; r < 4; ++r){
                        int rowRel = mi*16 + quad*4 + r;
                        float in1 = nsh[q*32 + rowRel];
                        cosT[rowRel*128 + colL] = acc[m][n][r] * in1 * in2;
                    }
                }
            }
        }
        __syncthreads();

        // all threads: streaming write-out of 32 rows x 128 cols
        #pragma unroll
        for (int i = 0; i < 4; ++i){
            int f = i*256 + t;           // float4 index 0..1023
            int rowRel = f >> 5;
            int c4 = f & 31;
            f32x4 cs4 = ((const f32x4*)cosT)[f];
            size_t idx = strideBase + (size_t)(q*32 + rowRel)*MDIM + c4*4;
            int4 z4 = *(const int4*)(zp + idx);

            f32x4 mk;
            float nl = 0.f;
            int   nc = 0;
            #pragma unroll
            for (int j = 0; j < 4; ++j){
                int zv = (&z4.x)[j];
                float cs = cs4[j];
                mk[j] = zv ? 1.0f : 0.0f;
                float y  = (float)zv * (tv*cs - bv);
                float nll = fmaxf(-y, 0.f) + __logf(1.0f + __expf(-fabsf(y)));
                nl += zv ? nll : 0.f;
                nc += zv ? 1 : 0;
            }
            lnum += nl;
            lcnt += nc;
            *(f32x4u*)(cosOut  + idx) = cs4;
            *(f32x4u*)(maskOut + idx) = mk;
        }
        if (q < 3) __syncthreads();      // before next strip overwrites cosT
    }

    // wave reduction, one atomic pair per wave
    #pragma unroll
    for (int off = 32; off > 0; off >>= 1){
        lnum += __shfl_down(lnum, off);
        lcnt += __shfl_down(lcnt, off);
    }
    if (lane == 0){
        atomicAdd(wsf, lnum);
        atomicAdd((int*)wsf + 1, lcnt);
    }
}

extern "C" void kernel_launch(void* const* d_in, const int* in_sizes, int n_in,
                              void* d_out, int out_size, void* d_ws, size_t ws_size,
                              hipStream_t stream) {
    const int*   zp = (const int*)  d_in[0];
    const float* x1 = (const float*)d_in[1];
    const float* x2 = (const float*)d_in[2];
    const float* tp = (const float*)d_in[3];
    const float* bp = (const float*)d_in[4];
    float* out = (float*)d_out;
    float* wsf = (float*)d_ws;

    ws_init_kernel<<<1, 1, 0, stream>>>(wsf);
    dim3 grid(MDIM/128, NDIM/128, BATCH);
    cossim_bce_main<<<grid, 256, 0, stream>>>(zp, x1, x2, tp, bp, out, wsf);
    finalize_kernel<<<1, 1, 0, stream>>>(wsf, out);
}

// Round 3
// 289.247 us; speedup vs baseline: 1.3860x; 1.3860x over previous
//
#include <hip/hip_runtime.h>
#include <hip/hip_bf16.h>

#define BATCH 8
#define NDIM  2048
#define MDIM  2048
#define CDIM  128

typedef __attribute__((ext_vector_type(8))) short bf16x8;
typedef __attribute__((ext_vector_type(4))) float f32x4;
// 4B-aligned float4 for the (out+1)-offset misaligned global stores
typedef __attribute__((ext_vector_type(4), aligned(4))) float f32x4u;

__device__ __forceinline__ float bf2f(unsigned int u16){
    union { unsigned int u; float f; } v; v.u = u16 << 16; return v.f;
}
__device__ __forceinline__ unsigned int f2bf(float f){
    union { float f; unsigned int u; } v; v.f = f;
    unsigned int u = v.u;
    u += 0x7FFFu + ((u >> 16) & 1u);   // round-to-nearest-even
    return u >> 16;
}

__global__ void ws_init_kernel(float* wsf){
    wsf[0] = 0.0f;          // loss numerator
    ((int*)wsf)[1] = 0;     // mask count
}

__global__ void finalize_kernel(const float* wsf, float* out){
    out[0] = wsf[0] / (float)(((const int*)wsf)[1]);
}

// launch_bounds(256,4): 128-VGPR cap. (256,5) capped at 102 and SPILLED the
// 64-reg accumulator (R2: VGPR_Count=48, FETCH +229MB scratch, dur 401us).
__global__ __launch_bounds__(256, 4) void cossim_bce_main(
    const int*  __restrict__ zp,
    const float* __restrict__ x1,
    const float* __restrict__ x2,
    const float* __restrict__ tparm,
    const float* __restrict__ bparm,
    float* __restrict__ out,
    float* __restrict__ wsf)
{
    // 32 KB LDS total.
    // lA/lB: 128x64 bf16 K-phase tiles (16 KB each), XOR-swizzled.
    // After GEMM: lA reused for norms (1 KB), lB reused for 32x128 f32 cos strip (16 KB).
    __shared__ __align__(16) unsigned short lA[128*64];
    __shared__ __align__(16) unsigned short lB[128*64];

    const int t  = threadIdx.x;
    const int bx = blockIdx.x;   // M tile
    const int by = blockIdx.y;   // N tile
    const int bz = blockIdx.z;   // batch

    const float tv = *tparm;
    const float bv = *bparm;

    const float* x1base = x1 + ((size_t)(bz*NDIM) + by*128) * CDIM;
    const float* x2base = x2 + ((size_t)(bz*MDIM) + bx*128) * CDIM;

    const int lane = t & 63;
    const int w    = t >> 6;
    const int wrow = (w >> 1) * 64;  // wave output row offset
    const int wcol = (w & 1) * 64;   // wave output col offset
    const int quad = lane >> 4;      // 0..3
    const int l16  = lane & 15;

    f32x4 acc[4][4];
    #pragma unroll
    for (int m = 0; m < 4; ++m)
        #pragma unroll
        for (int n = 0; n < 4; ++n)
            acc[m][n] = (f32x4){0.f, 0.f, 0.f, 0.f};

    float nsum = 0.f;                // per-thread norm partial (row t&127 of A or B)
    const int nrow = t & 127;

    // ---- two K-phases of 64 ----
    #pragma unroll
    for (int ph = 0; ph < 2; ++ph){
        // stage: f32 -> bf16, swizzled LDS writes (chunk ^ row&7)
        #pragma unroll
        for (int i = 0; i < 4; ++i){
            int chunk = i*256 + t;       // 1024 16B-chunks per tile
            int row = chunk >> 3;        // 0..127
            int pos = chunk & 7;         // 16B chunk within 64-col row
            int sw  = pos ^ (row & 7);
            {
                const float* p = x1base + row*CDIM + ph*64 + pos*8;
                float4 a = *(const float4*)p;
                float4 b = *(const float4*)(p + 4);
                uint4 pk;
                pk.x = f2bf(a.x) | (f2bf(a.y) << 16);
                pk.y = f2bf(a.z) | (f2bf(a.w) << 16);
                pk.z = f2bf(b.x) | (f2bf(b.y) << 16);
                pk.w = f2bf(b.z) | (f2bf(b.w) << 16);
                ((uint4*)lA)[row*8 + sw] = pk;
            }
            {
                const float* p = x2base + row*CDIM + ph*64 + pos*8;
                float4 a = *(const float4*)p;
                float4 b = *(const float4*)(p + 4);
                uint4 pk;
                pk.x = f2bf(a.x) | (f2bf(a.y) << 16);
                pk.y = f2bf(a.z) | (f2bf(a.w) << 16);
                pk.z = f2bf(b.x) | (f2bf(b.y) << 16);
                pk.w = f2bf(b.z) | (f2bf(b.w) << 16);
                ((uint4*)lB)[row*8 + sw] = pk;
            }
        }
        __syncthreads();

        // MFMA: 2 k-steps of 32 per phase
        #pragma unroll
        for (int kk = 0; kk < 2; ++kk){
            const int kc = kk*4 + quad;          // 16B k-chunk 0..7
            bf16x8 afr[4], bfr[4];
            #pragma unroll
            for (int m = 0; m < 4; ++m){
                int row = wrow + m*16 + l16;
                afr[m] = ((const bf16x8*)lA)[row*8 + (kc ^ (row & 7))];
            }
            #pragma unroll
            for (int n = 0; n < 4; ++n){
                int row = wcol + n*16 + l16;
                bfr[n] = ((const bf16x8*)lB)[row*8 + (kc ^ (row & 7))];
            }
            #pragma unroll
            for (int m = 0; m < 4; ++m)
                #pragma unroll
                for (int n = 0; n < 4; ++n)
                    acc[m][n] = __builtin_amdgcn_mfma_f32_16x16x32_bf16(
                                    afr[m], bfr[n], acc[m][n], 0, 0, 0);
        }

        // norm partials from the bf16 tiles (one row per thread)
        {
            const unsigned short* src = (t < 128) ? lA : lB;
            #pragma unroll
            for (int c = 0; c < 8; ++c){
                uint4 v = ((const uint4*)src)[nrow*8 + (c ^ (nrow & 7))];
                float f0 = bf2f(v.x & 0xffffu), f1 = bf2f(v.x >> 16);
                float f2 = bf2f(v.y & 0xffffu), f3 = bf2f(v.y >> 16);
                float f4 = bf2f(v.z & 0xffffu), f5 = bf2f(v.z >> 16);
                float f6 = bf2f(v.w & 0xffffu), f7 = bf2f(v.w >> 16);
                nsum += f0*f0 + f1*f1 + f2*f2 + f3*f3 + f4*f4 + f5*f5 + f6*f6 + f7*f7;
            }
        }
        __syncthreads();   // tile reads done before restage / nsh reuse
    }

    // ---- norms into LDS (reuse lA) ----
    float* nsh = (float*)lA;         // [0..127]=1/||x1 row||, [128..255]=1/||x2 row||
    nsh[t] = 1.0f / sqrtf(fmaxf(nsum, 1e-16f));
    __syncthreads();

    // ---- epilogue: 4 strips of 32 rows via LDS transpose (reuse lB) ----
    float* cosT = (float*)lB;        // [32][128] f32
    float* cosOut  = out + 1;
    float* maskOut = out + 1 + (size_t)BATCH*NDIM*MDIM;
    const size_t strideBase = (size_t)bz*NDIM*MDIM + (size_t)(by*128)*MDIM + (size_t)(bx*128);

    float lnum = 0.f;
    int   lcnt = 0;

    // prefetch z for strip 0 (latency hides under producer writes + barrier)
    int4 zpre[4];
    #pragma unroll
    for (int i = 0; i < 4; ++i){
        int f = i*256 + t;
        int rowRel = f >> 5;
        int c4 = f & 31;
        zpre[i] = *(const int4*)(zp + strideBase + (size_t)rowRel*MDIM + c4*4);
    }

    #pragma unroll
    for (int q = 0; q < 4; ++q){
        // producers: waves owning rows q*32 .. q*32+31
        if ((w >> 1) == (q >> 1)){
            #pragma unroll
            for (int mi = 0; mi < 2; ++mi){
                int m = (q & 1)*2 + mi;
                #pragma unroll
                for (int n = 0; n < 4; ++n){
                    int colL = wcol + n*16 + l16;
                    float in2 = nsh[128 + colL];
                    #pragma unroll
                    for (int r = 0; r < 4; ++r){
                        int rowRel = mi*16 + quad*4 + r;
                        float in1 = nsh[q*32 + rowRel];
                        cosT[rowRel*128 + colL] = acc[m][n][r] * in1 * in2;
                    }
                }
            }
        }
        __syncthreads();

        // all threads: streaming write-out of 32 rows x 128 cols
        #pragma unroll
        for (int i = 0; i < 4; ++i){
            int f = i*256 + t;           // float4 index 0..1023
            int rowRel = f >> 5;
            int c4 = f & 31;
            size_t idx = strideBase + (size_t)(q*32 + rowRel)*MDIM + c4*4;

            int4 z4 = zpre[i];
            if (q < 3)                   // issue next strip's z load NOW
                zpre[i] = *(const int4*)(zp + idx + (size_t)32*MDIM);

            f32x4 cs4 = ((const f32x4*)cosT)[f];

            f32x4 mk;
            float nl = 0.f;
            int   nc = 0;
            #pragma unroll
            for (int j = 0; j < 4; ++j){
                int zv = (&z4.x)[j];
                float cs = cs4[j];
                mk[j] = zv ? 1.0f : 0.0f;
                float y  = (float)zv * (tv*cs - bv);
                float nll = fmaxf(-y, 0.f) + __logf(1.0f + __expf(-fabsf(y)));
                nl += zv ? nll : 0.f;
                nc += zv ? 1 : 0;
            }
            lnum += nl;
            lcnt += nc;
            __builtin_nontemporal_store(*(f32x4u*)&cs4, (f32x4u*)(cosOut  + idx));
            __builtin_nontemporal_store(*(f32x4u*)&mk,  (f32x4u*)(maskOut + idx));
        }
        if (q < 3) __syncthreads();      // before next strip overwrites cosT
    }

    // wave reduction, one atomic pair per wave
    #pragma unroll
    for (int off = 32; off > 0; off >>= 1){
        lnum += __shfl_down(lnum, off);
        lcnt += __shfl_down(lcnt, off);
    }
    if (lane == 0){
        atomicAdd(wsf, lnum);
        atomicAdd((int*)wsf + 1, lcnt);
    }
}

extern "C" void kernel_launch(void* const* d_in, const int* in_sizes, int n_in,
                              void* d_out, int out_size, void* d_ws, size_t ws_size,
                              hipStream_t stream) {
    const int*   zp = (const int*)  d_in[0];
    const float* x1 = (const float*)d_in[1];
    const float* x2 = (const float*)d_in[2];
    const float* tp = (const float*)d_in[3];
    const float* bp = (const float*)d_in[4];
    float* out = (float*)d_out;
    float* wsf = (float*)d_ws;

    ws_init_kernel<<<1, 1, 0, stream>>>(wsf);
    dim3 grid(MDIM/128, NDIM/128, BATCH);
    cossim_bce_main<<<grid, 256, 0, stream>>>(zp, x1, x2, tp, bp, out, wsf);
    finalize_kernel<<<1, 1, 0, stream>>>(wsf, out);
}